// Round 1
// baseline (637.477 us; speedup 1.0000x reference)
//
#include <hip/hip_runtime.h>

#define N 8192
#define L 13
#define RS 24        // padded row stride (floats) in packed [coords|q] buffer
#define QOFF 8       // q starts at float offset 8 (32B-aligned for float4)
#define CH 128       // p' rows staged to LDS per chunk
#define SEGS 16
#define SEGLEN (N / SEGS)

// pk row layout (24 floats): [0..5]=coords (xyz,feat), [6..7]=pad, [8..20]=q[13], [21..23]=pad

__global__ __launch_bounds__(256) void prep_kernel(const float* __restrict__ points,
                                                   const float* __restrict__ logits,
                                                   float* __restrict__ pk,
                                                   float* __restrict__ cur) {
  int p = blockIdx.x * 256 + threadIdx.x;
  if (p < N) {
#pragma unroll
    for (int d = 0; d < 6; ++d) pk[p * RS + d] = points[p * 6 + d];
    pk[p * RS + 6] = 0.f; pk[p * RS + 7] = 0.f;
    pk[p * RS + 21] = 0.f; pk[p * RS + 22] = 0.f; pk[p * RS + 23] = 0.f;
#pragma unroll
    for (int l = 0; l < L; ++l) cur[p * L + l] = logits[p * L + l];
  }
}

__global__ void mprep_kernel(const float* __restrict__ Ws, const float* __restrict__ Wb,
                             const float* __restrict__ C, float* __restrict__ M1,
                             float* __restrict__ M2) {
  int i = threadIdx.x;
  if (i < L * L) {
    int r = i / L, c = i % L;
    float a = 0.f, b = 0.f;
    for (int j = 0; j < L; ++j) {
      a += C[r * L + j] * Ws[j * L + c];
      b += C[r * L + j] * Wb[j * L + c];
    }
    M1[i] = a; M2[i] = b;
  }
}

// softmax over axis 0 (points) for one label column per block; writes q into pk
__global__ __launch_bounds__(256) void softmax_kernel(const float* __restrict__ cur,
                                                      float* __restrict__ pk) {
  int l = blockIdx.x, tid = threadIdx.x;
  __shared__ float red[256];
  float m = -1e30f;
  for (int p = tid; p < N; p += 256) m = fmaxf(m, cur[p * L + l]);
  red[tid] = m; __syncthreads();
  for (int s = 128; s > 0; s >>= 1) {
    if (tid < s) red[tid] = fmaxf(red[tid], red[tid + s]);
    __syncthreads();
  }
  m = red[0]; __syncthreads();
  float sum = 0.f;
  for (int p = tid; p < N; p += 256) {
    float e = __builtin_amdgcn_exp2f((cur[p * L + l] - m) * 1.44269504f);
    pk[p * RS + QOFF + l] = e;
    sum += e;
  }
  red[tid] = sum; __syncthreads();
  for (int s = 128; s > 0; s >>= 1) {
    if (tid < s) red[tid] += red[tid + s];
    __syncthreads();
  }
  float inv = 1.0f / red[0];
  for (int p = tid; p < N; p += 256) pk[p * RS + QOFF + l] *= inv;
}

// hot kernel: each thread owns one output point p, accumulates over its p' segment
__global__ __launch_bounds__(256) void filter_kernel(const float* __restrict__ pk,
                                                     float* __restrict__ partials) {
  int tid = threadIdx.x;
  int p = blockIdx.x * 256 + tid;
  int seg = blockIdx.y;
  __shared__ float sm[CH * RS];

  float cx0 = pk[p * RS + 0], cx1 = pk[p * RS + 1], cx2 = pk[p * RS + 2];
  float cf0 = pk[p * RS + 3], cf1 = pk[p * RS + 4], cf2 = pk[p * RS + 5];

  float sf[L], bf[L], ns = 0.f, nb = 0.f;
#pragma unroll
  for (int l = 0; l < L; ++l) { sf[l] = 0.f; bf[l] = 0.f; }

  for (int c0 = 0; c0 < SEGLEN; c0 += CH) {
    __syncthreads();
    const float4* src = (const float4*)(pk + (size_t)(seg * SEGLEN + c0) * RS);
    float4* dst = (float4*)sm;
#pragma unroll
    for (int k = 0; k < (CH * RS / 4) / 256; ++k) dst[tid + 256 * k] = src[tid + 256 * k];
    __syncthreads();

#pragma unroll 2
    for (int j = 0; j < CH; ++j) {
      const float* row = sm + j * RS;
      float dx0 = cx0 - row[0], dx1 = cx1 - row[1], dx2 = cx2 - row[2];
      float d2x = dx0 * dx0 + dx1 * dx1 + dx2 * dx2;
      float f0 = cf0 - row[3], f1 = cf1 - row[4], f2 = cf2 - row[5];
      float d2b = d2x + f0 * f0 + f1 * f1 + f2 * f2;
      d2x = fmaxf(d2x, 0.f);
      d2b = fmaxf(d2b, 0.f);
      // exp(-0.5*d2) = exp2(d2 * -0.5/ln2)
      float es = __builtin_amdgcn_exp2f(d2x * -0.72134752044f);
      float eb = __builtin_amdgcn_exp2f(d2b * -0.72134752044f);
      ns += es; nb += eb;
#pragma unroll
      for (int l = 0; l < L; ++l) {
        float q = row[QOFF + l];
        sf[l] = fmaf(es, q, sf[l]);
        bf[l] = fmaf(eb, q, bf[l]);
      }
    }
  }

  size_t b = (size_t)seg * 28 * N + p;  // layout [seg][28][N] -> coalesced
#pragma unroll
  for (int l = 0; l < L; ++l) {
    partials[b + (size_t)l * N] = sf[l];
    partials[b + (size_t)(13 + l) * N] = bf[l];
  }
  partials[b + (size_t)26 * N] = ns;
  partials[b + (size_t)27 * N] = nb;
}

__global__ __launch_bounds__(256) void reduce_kernel(const float* __restrict__ partials,
                                                     float* __restrict__ S,
                                                     float* __restrict__ Bb) {
  int p = blockIdx.x * 256 + threadIdx.x;
  float acc[28];
#pragma unroll
  for (int k = 0; k < 28; ++k) acc[k] = 0.f;
  for (int seg = 0; seg < SEGS; ++seg) {
    const float* base = partials + (size_t)seg * 28 * N + p;
#pragma unroll
    for (int k = 0; k < 28; ++k) acc[k] += base[(size_t)k * N];
  }
  float is = 1.0f / acc[26], ib = 1.0f / acc[27];
#pragma unroll
  for (int l = 0; l < L; ++l) {
    S[p * L + l] = acc[l] * is;
    Bb[p * L + l] = acc[13 + l] * ib;
  }
}

// faithful reshape-mixing: out.flat[i] = sum_j M1[r,j]*S.flat[j*N+c] + M2[r,j]*B.flat[j*N+c]
// with r = i/8192, c = i%8192; then + logits
__global__ __launch_bounds__(256) void mix_kernel(const float* __restrict__ S,
                                                  const float* __restrict__ Bb,
                                                  const float* __restrict__ M1,
                                                  const float* __restrict__ M2,
                                                  const float* __restrict__ logits,
                                                  float* __restrict__ cur) {
  int i = blockIdx.x * 256 + threadIdx.x;
  if (i >= N * L) return;
  int r = i >> 13;
  int c = i & (N - 1);
  float v = 0.f;
#pragma unroll
  for (int j = 0; j < L; ++j) {
    v = fmaf(M1[r * L + j], S[j * N + c], v);
    v = fmaf(M2[r * L + j], Bb[j * N + c], v);
  }
  cur[i] = v + logits[i];
}

extern "C" void kernel_launch(void* const* d_in, const int* in_sizes, int n_in,
                              void* d_out, int out_size, void* d_ws, size_t ws_size,
                              hipStream_t stream) {
  const float* points = (const float*)d_in[0];
  const float* logits = (const float*)d_in[1];
  const float* Ws = (const float*)d_in[2];
  const float* Wb = (const float*)d_in[3];
  const float* C = (const float*)d_in[4];

  float* cur = (float*)d_out;            // cur_logits lives in d_out
  float* pk = (float*)d_ws;              // N*RS
  float* partials = pk + (size_t)N * RS; // SEGS*28*N
  float* S = partials + (size_t)SEGS * 28 * N;
  float* Bb = S + (size_t)N * L;
  float* M1 = Bb + (size_t)N * L;
  float* M2 = M1 + L * L;

  prep_kernel<<<N / 256, 256, 0, stream>>>(points, logits, pk, cur);
  mprep_kernel<<<1, 256, 0, stream>>>(Ws, Wb, C, M1, M2);

  for (int it = 0; it < 5; ++it) {
    softmax_kernel<<<L, 256, 0, stream>>>(cur, pk);
    filter_kernel<<<dim3(N / 256, SEGS), 256, 0, stream>>>(pk, partials);
    reduce_kernel<<<N / 256, 256, 0, stream>>>(partials, S, Bb);
    mix_kernel<<<(N * L + 255) / 256, 256, 0, stream>>>(S, Bb, M1, M2, logits, cur);
  }
}

// Round 2
// 412.845 us; speedup vs baseline: 1.5441x; 1.5441x over previous
//
#include <hip/hip_runtime.h>

#define N 8192
#define L 13
#define SEGS 8
#define SEGLEN (N / SEGS)

typedef __bf16 bf16x8 __attribute__((ext_vector_type(8)));
typedef float f32x4 __attribute__((ext_vector_type(4)));

// crd: SoA coords, crd[dim*N + p], dims 0..2 = xyz, 3..5 = feat
// qpack: bf16 B-fragments, [kc(256)][lane(64)][j(8)] u16; value = q[kc*32 + (lane>>4)*8 + j][lane&15]
//        col 13 = 1.0 (norm column), cols 14/15 = 0

__global__ __launch_bounds__(256) void prep_kernel(const float* __restrict__ points,
                                                   const float* __restrict__ logits,
                                                   float* __restrict__ crd,
                                                   float* __restrict__ cur,
                                                   unsigned short* __restrict__ qpack) {
  int p = blockIdx.x * 256 + threadIdx.x;
#pragma unroll
  for (int d = 0; d < 6; ++d) crd[d * N + p] = points[p * 6 + d];
#pragma unroll
  for (int l = 0; l < L; ++l) cur[p * L + l] = logits[p * L + l];
  int kc = p >> 5, g = (p & 31) >> 3, j = p & 7;
  size_t base = ((size_t)kc * 64 + g * 16) * 8 + j;
  qpack[base + 13 * 8] = 0x3F80;  // bf16 1.0
  qpack[base + 14 * 8] = 0;
  qpack[base + 15 * 8] = 0;
}

__global__ void mprep_kernel(const float* __restrict__ Ws, const float* __restrict__ Wb,
                             const float* __restrict__ C, float* __restrict__ M1,
                             float* __restrict__ M2) {
  int i = threadIdx.x;
  if (i < L * L) {
    int r = i / L, c = i % L;
    float a = 0.f, b = 0.f;
    for (int j = 0; j < L; ++j) {
      a += C[r * L + j] * Ws[j * L + c];
      b += C[r * L + j] * Wb[j * L + c];
    }
    M1[i] = a; M2[i] = b;
  }
}

// softmax over axis 0 (points) for one label column per block; packs bf16 B-fragments
__global__ __launch_bounds__(256) void softmax_kernel(const float* __restrict__ cur,
                                                      float* __restrict__ qtmp,
                                                      unsigned short* __restrict__ qpack) {
  int l = blockIdx.x, tid = threadIdx.x;
  __shared__ float red[256];
  float m = -1e30f;
  for (int p = tid; p < N; p += 256) m = fmaxf(m, cur[p * L + l]);
  red[tid] = m; __syncthreads();
  for (int s = 128; s > 0; s >>= 1) {
    if (tid < s) red[tid] = fmaxf(red[tid], red[tid + s]);
    __syncthreads();
  }
  m = red[0]; __syncthreads();
  float sum = 0.f;
  for (int p = tid; p < N; p += 256) {
    float e = __builtin_amdgcn_exp2f((cur[p * L + l] - m) * 1.44269504f);
    qtmp[l * N + p] = e;
    sum += e;
  }
  red[tid] = sum; __syncthreads();
  for (int s = 128; s > 0; s >>= 1) {
    if (tid < s) red[tid] += red[tid + s];
    __syncthreads();
  }
  float inv = 1.0f / red[0];
  for (int p = tid; p < N; p += 256) {
    float q = qtmp[l * N + p] * inv;
    unsigned int b = __float_as_uint(q);
    b += 0x7FFF + ((b >> 16) & 1);  // RNE to bf16 (q >= 0, no NaN)
    int kc = p >> 5, g = (p & 31) >> 3, j = p & 7;
    qpack[((size_t)kc * 64 + g * 16 + l) * 8 + j] = (unsigned short)(b >> 16);
  }
}

// hot kernel: 4 waves/block, each wave owns 16 p-rows; MFMA accumulates labels + norm
__global__ __launch_bounds__(256) void filter_kernel(const float* __restrict__ crd,
                                                     const unsigned short* __restrict__ qpack,
                                                     float* __restrict__ ps,
                                                     float* __restrict__ pb) {
  int tid = threadIdx.x;
  int lane = tid & 63, wave = tid >> 6;
  int g = lane >> 4, rm = lane & 15;
  int prow = blockIdx.x * 64 + wave * 16 + rm;
  int seg = blockIdx.y;

  float xp0 = crd[prow],       xp1 = crd[N + prow],     xp2 = crd[2 * N + prow];
  float fp0 = crd[3 * N + prow], fp1 = crd[4 * N + prow], fp2 = crd[5 * N + prow];

  f32x4 acc_s = {0.f, 0.f, 0.f, 0.f};
  f32x4 acc_b = {0.f, 0.f, 0.f, 0.f};
  const bf16x8* qp = (const bf16x8*)qpack;

  for (int kb = seg * SEGLEN; kb < (seg + 1) * SEGLEN; kb += 32) {
    int k0 = kb + g * 8;
    float xs[8], ys[8], zs[8], us[8], vs[8], ws_[8];
    *(float4*)(xs)     = *(const float4*)(crd + k0);
    *(float4*)(xs + 4) = *(const float4*)(crd + k0 + 4);
    *(float4*)(ys)     = *(const float4*)(crd + N + k0);
    *(float4*)(ys + 4) = *(const float4*)(crd + N + k0 + 4);
    *(float4*)(zs)     = *(const float4*)(crd + 2 * N + k0);
    *(float4*)(zs + 4) = *(const float4*)(crd + 2 * N + k0 + 4);
    *(float4*)(us)     = *(const float4*)(crd + 3 * N + k0);
    *(float4*)(us + 4) = *(const float4*)(crd + 3 * N + k0 + 4);
    *(float4*)(vs)     = *(const float4*)(crd + 4 * N + k0);
    *(float4*)(vs + 4) = *(const float4*)(crd + 4 * N + k0 + 4);
    *(float4*)(ws_)     = *(const float4*)(crd + 5 * N + k0);
    *(float4*)(ws_ + 4) = *(const float4*)(crd + 5 * N + k0 + 4);

    float es[8], eb[8];
#pragma unroll
    for (int j = 0; j < 8; ++j) {
      float d0 = xp0 - xs[j], d1 = xp1 - ys[j], d2 = xp2 - zs[j];
      float d2x = d0 * d0 + d1 * d1 + d2 * d2;
      float e0 = fp0 - us[j], e1 = fp1 - vs[j], e2 = fp2 - ws_[j];
      float d2b = d2x + e0 * e0 + e1 * e1 + e2 * e2;
      // exp(-0.5*d2) = exp2(d2 * -0.5/ln2); d2 >= 0 by construction
      es[j] = __builtin_amdgcn_exp2f(d2x * -0.72134752044448f);
      eb[j] = __builtin_amdgcn_exp2f(d2b * -0.72134752044448f);
    }
    bf16x8 fa, fb;
#pragma unroll
    for (int j = 0; j < 8; ++j) { fa[j] = (__bf16)es[j]; fb[j] = (__bf16)eb[j]; }
    bf16x8 bq = qp[(size_t)(kb >> 5) * 64 + lane];
    acc_s = __builtin_amdgcn_mfma_f32_16x16x32_bf16(fa, bq, acc_s, 0, 0, 0);
    acc_b = __builtin_amdgcn_mfma_f32_16x16x32_bf16(fb, bq, acc_b, 0, 0, 0);
  }

  // C/D layout: col = lane&15, row = (lane>>4)*4 + r  [m89-verified]
  int pout = blockIdx.x * 64 + wave * 16 + g * 4;
  size_t base = ((size_t)seg * N + pout) * 16 + rm;
#pragma unroll
  for (int r = 0; r < 4; ++r) {
    ps[base + (size_t)r * 16] = acc_s[r];
    pb[base + (size_t)r * 16] = acc_b[r];
  }
}

__global__ __launch_bounds__(256) void reduce_kernel(const float* __restrict__ ps,
                                                     const float* __restrict__ pb,
                                                     float* __restrict__ S,
                                                     float* __restrict__ Bb) {
  int p = blockIdx.x * 256 + threadIdx.x;
  f32x4 s0 = {0,0,0,0}, s1 = {0,0,0,0}, s2 = {0,0,0,0}, s3 = {0,0,0,0};
  f32x4 b0 = {0,0,0,0}, b1 = {0,0,0,0}, b2 = {0,0,0,0}, b3 = {0,0,0,0};
  for (int seg = 0; seg < SEGS; ++seg) {
    const f32x4* rs = (const f32x4*)(ps + ((size_t)seg * N + p) * 16);
    const f32x4* rb = (const f32x4*)(pb + ((size_t)seg * N + p) * 16);
    s0 += rs[0]; s1 += rs[1]; s2 += rs[2]; s3 += rs[3];
    b0 += rb[0]; b1 += rb[1]; b2 += rb[2]; b3 += rb[3];
  }
  float inv_s = 1.0f / s3[1];  // col 13 = norm
  float inv_b = 1.0f / b3[1];
  float sa[16], ba[16];
  *(f32x4*)(sa) = s0; *(f32x4*)(sa + 4) = s1; *(f32x4*)(sa + 8) = s2; *(f32x4*)(sa + 12) = s3;
  *(f32x4*)(ba) = b0; *(f32x4*)(ba + 4) = b1; *(f32x4*)(ba + 8) = b2; *(f32x4*)(ba + 12) = b3;
#pragma unroll
  for (int l = 0; l < L; ++l) {
    S[p * L + l] = sa[l] * inv_s;
    Bb[p * L + l] = ba[l] * inv_b;
  }
}

// faithful reshape-mixing (identical to verified v1)
__global__ __launch_bounds__(256) void mix_kernel(const float* __restrict__ S,
                                                  const float* __restrict__ Bb,
                                                  const float* __restrict__ M1,
                                                  const float* __restrict__ M2,
                                                  const float* __restrict__ logits,
                                                  float* __restrict__ cur) {
  int i = blockIdx.x * 256 + threadIdx.x;
  if (i >= N * L) return;
  int r = i >> 13;
  int c = i & (N - 1);
  float v = 0.f;
#pragma unroll
  for (int j = 0; j < L; ++j) {
    v = fmaf(M1[r * L + j], S[j * N + c], v);
    v = fmaf(M2[r * L + j], Bb[j * N + c], v);
  }
  cur[i] = v + logits[i];
}

extern "C" void kernel_launch(void* const* d_in, const int* in_sizes, int n_in,
                              void* d_out, int out_size, void* d_ws, size_t ws_size,
                              hipStream_t stream) {
  const float* points = (const float*)d_in[0];
  const float* logits = (const float*)d_in[1];
  const float* Ws = (const float*)d_in[2];
  const float* Wb = (const float*)d_in[3];
  const float* C = (const float*)d_in[4];

  float* cur = (float*)d_out;

  float* w = (float*)d_ws;
  float* crd  = w;                       w += 6 * N;
  float* qtmp = w;                       w += (size_t)L * N;
  float* ps   = w;                       w += (size_t)SEGS * N * 16;
  float* pb   = w;                       w += (size_t)SEGS * N * 16;
  float* S    = w;                       w += (size_t)L * N;
  float* Bb   = w;                       w += (size_t)L * N;
  float* M1   = w;                       w += 256;
  float* M2   = w;                       w += 256;
  unsigned short* qpack = (unsigned short*)w;  // 8192*16 u16 = 256 KB

  prep_kernel<<<N / 256, 256, 0, stream>>>(points, logits, crd, cur, qpack);
  mprep_kernel<<<1, 256, 0, stream>>>(Ws, Wb, C, M1, M2);

  for (int it = 0; it < 5; ++it) {
    softmax_kernel<<<L, 256, 0, stream>>>(cur, qtmp, qpack);
    filter_kernel<<<dim3(N / 64, SEGS), 256, 0, stream>>>(crd, qpack, ps, pb);
    reduce_kernel<<<N / 256, 256, 0, stream>>>(ps, pb, S, Bb);
    mix_kernel<<<(N * L + 255) / 256, 256, 0, stream>>>(S, Bb, M1, M2, logits, cur);
  }
}

// Round 3
// 347.362 us; speedup vs baseline: 1.8352x; 1.1885x over previous
//
#include <hip/hip_runtime.h>

#define N 8192
#define L 13

typedef _Float16 f16x8 __attribute__((ext_vector_type(8)));
typedef float f32x4 __attribute__((ext_vector_type(4)));

// ws layouts:
// crd[d*N+p] f32 SoA coords; snx[p]=|xyz|^2, snf[p]=|feat|^2 (f32)
// a1pack: [subtile s(512)][lane(64)][j(8)] f16 — A-frag for dot MFMA:
//   lane = g*16 + r holds row r (k-point = s*16+r); g==0: j=0..2 -> xyz, g==1: j=0..2 -> feat, else 0
// qpack: [kc(256)][lane = g*16+col (64)][j(8)] f16 — B-frag for acc MFMA:
//   value = q[kc*32 + phys(g,j)][col], phys(g,j) = j<4 ? 4g+j : 16+4g+(j-4)
//   col 13 = 1.0 (norm column), cols 14/15 = 0

__global__ __launch_bounds__(256) void prep_kernel(const float* __restrict__ points,
                                                   const float* __restrict__ logits,
                                                   float* __restrict__ crd,
                                                   float* __restrict__ cur,
                                                   float* __restrict__ snx,
                                                   float* __restrict__ snf,
                                                   unsigned short* __restrict__ a1pack,
                                                   unsigned short* __restrict__ qpack) {
  int p = blockIdx.x * 256 + threadIdx.x;
  float c[6];
#pragma unroll
  for (int d = 0; d < 6; ++d) { c[d] = points[p * 6 + d]; crd[d * N + p] = c[d]; }
  snx[p] = c[0] * c[0] + c[1] * c[1] + c[2] * c[2];
  snf[p] = c[3] * c[3] + c[4] * c[4] + c[5] * c[5];
#pragma unroll
  for (int l = 0; l < L; ++l) cur[p * L + l] = logits[p * L + l];

  // a1pack rows for this point: subtile s = p>>4, row r = p&15
  int s = p >> 4, r = p & 15;
  unsigned short h[6];
#pragma unroll
  for (int d = 0; d < 6; ++d) { _Float16 hv = (_Float16)c[d]; h[d] = *(unsigned short*)&hv; }
#pragma unroll
  for (int g = 0; g < 4; ++g) {
    size_t base = ((size_t)s * 64 + g * 16 + r) * 8;
#pragma unroll
    for (int j = 0; j < 8; ++j) {
      unsigned short v = 0;
      if (g == 0 && j < 3) v = h[j];
      if (g == 1 && j < 3) v = h[3 + j];
      a1pack[base + j] = v;
    }
  }

  // qpack constant columns: thread p covers (kc = p>>5, one (g,j) combo = p&31)
  int kc = p >> 5, kk = p & 31;
  int g = (kk < 16) ? (kk >> 2) : ((kk - 16) >> 2);
  int j = (kk < 16) ? (kk & 3) : (4 + (kk & 3));
  qpack[((size_t)kc * 64 + g * 16 + 13) * 8 + j] = 0x3C00;  // f16 1.0
  qpack[((size_t)kc * 64 + g * 16 + 14) * 8 + j] = 0;
  qpack[((size_t)kc * 64 + g * 16 + 15) * 8 + j] = 0;
}

__global__ void mprep_kernel(const float* __restrict__ Ws, const float* __restrict__ Wb,
                             const float* __restrict__ C, float* __restrict__ M1,
                             float* __restrict__ M2) {
  int i = threadIdx.x;
  if (i < L * L) {
    int r = i / L, c = i % L;
    float a = 0.f, b = 0.f;
    for (int j = 0; j < L; ++j) {
      a += C[r * L + j] * Ws[j * L + c];
      b += C[r * L + j] * Wb[j * L + c];
    }
    M1[i] = a; M2[i] = b;
  }
}

// softmax over axis 0 (points) per label column; packs f16 B-fragments with phys(g,j) mapping
__global__ __launch_bounds__(1024) void softmax_kernel(const float* __restrict__ cur,
                                                       float* __restrict__ qtmp,
                                                       unsigned short* __restrict__ qpack) {
  int l = blockIdx.x, tid = threadIdx.x;
  __shared__ float red[1024];
  float m = -1e30f;
  for (int p = tid; p < N; p += 1024) m = fmaxf(m, cur[p * L + l]);
  red[tid] = m; __syncthreads();
  for (int s = 512; s > 0; s >>= 1) {
    if (tid < s) red[tid] = fmaxf(red[tid], red[tid + s]);
    __syncthreads();
  }
  m = red[0]; __syncthreads();
  float sum = 0.f;
  for (int p = tid; p < N; p += 1024) {
    float e = __builtin_amdgcn_exp2f((cur[p * L + l] - m) * 1.44269504f);
    qtmp[l * N + p] = e;
    sum += e;
  }
  red[tid] = sum; __syncthreads();
  for (int s = 512; s > 0; s >>= 1) {
    if (tid < s) red[tid] += red[tid + s];
    __syncthreads();
  }
  float inv = 1.0f / red[0];
  for (int p = tid; p < N; p += 1024) {
    _Float16 q = (_Float16)(qtmp[l * N + p] * inv);
    int kc = p >> 5, kk = p & 31;
    int g = (kk < 16) ? (kk >> 2) : ((kk - 16) >> 2);
    int j = (kk < 16) ? (kk & 3) : (4 + (kk & 3));
    qpack[((size_t)kc * 64 + g * 16 + l) * 8 + j] = *(unsigned short*)&q;
  }
}

// hot kernel: 4 independent waves/block, each owns 16 p-rows.
// Dot MFMAs compute -2*(cross dots); f32 VALU adds norms; exp; acc MFMAs accumulate labels+norm.
__global__ __launch_bounds__(256) void filter_kernel(const float* __restrict__ crd,
                                                     const float* __restrict__ snx,
                                                     const float* __restrict__ snf,
                                                     const unsigned short* __restrict__ a1pack,
                                                     const unsigned short* __restrict__ qpack,
                                                     float* __restrict__ ps,
                                                     float* __restrict__ pb,
                                                     int segs) {
  int tid = threadIdx.x;
  int lane = tid & 63, wave = tid >> 6;
  int g = lane >> 4, rm = lane & 15;
  int ptile = blockIdx.x * 64 + wave * 16;
  int p = ptile + rm;
  int seg = blockIdx.y;
  int seglen = N / segs;

  // loop-invariant B-fragments (p-side coords, -2x folded)
  f16x8 b1x = {0, 0, 0, 0, 0, 0, 0, 0};
  f16x8 b1f = {0, 0, 0, 0, 0, 0, 0, 0};
  if (g == 0) {
#pragma unroll
    for (int d = 0; d < 3; ++d) b1x[d] = (_Float16)(-2.0f * crd[d * N + p]);
  } else if (g == 1) {
#pragma unroll
    for (int d = 0; d < 3; ++d) b1f[d] = (_Float16)(-2.0f * crd[(3 + d) * N + p]);
  }
  float sxp = snx[p], sfp = snf[p];

  f32x4 acc_s = {0.f, 0.f, 0.f, 0.f};
  f32x4 acc_b = {0.f, 0.f, 0.f, 0.f};
  const f32x4 zero = {0.f, 0.f, 0.f, 0.f};
  const f16x8* a1 = (const f16x8*)a1pack;
  const f16x8* qp = (const f16x8*)qpack;

  int kend = (seg + 1) * seglen;
  for (int kb = seg * seglen; kb < kend; kb += 32) {
    int s0 = kb >> 4;
    f16x8 A0 = a1[(size_t)s0 * 64 + lane];
    f16x8 A1_ = a1[(size_t)(s0 + 1) * 64 + lane];
    f16x8 bq = qp[(size_t)(kb >> 5) * 64 + lane];
    f32x4 nx0 = *(const f32x4*)(snx + kb + 4 * g);
    f32x4 nf0 = *(const f32x4*)(snf + kb + 4 * g);
    f32x4 nx1 = *(const f32x4*)(snx + kb + 16 + 4 * g);
    f32x4 nf1 = *(const f32x4*)(snf + kb + 16 + 4 * g);

    f32x4 gx0 = __builtin_amdgcn_mfma_f32_16x16x32_f16(A0, b1x, zero, 0, 0, 0);
    f32x4 gf0 = __builtin_amdgcn_mfma_f32_16x16x32_f16(A0, b1f, zero, 0, 0, 0);
    f32x4 gx1 = __builtin_amdgcn_mfma_f32_16x16x32_f16(A1_, b1x, zero, 0, 0, 0);
    f32x4 gf1 = __builtin_amdgcn_mfma_f32_16x16x32_f16(A1_, b1f, zero, 0, 0, 0);

    f16x8 a2s, a2b;
#pragma unroll
    for (int r = 0; r < 4; ++r) {
      float d2x = fmaxf(sxp + nx0[r] + gx0[r], 0.f);
      float d2b = fmaxf(d2x + (sfp + nf0[r] + gf0[r]), 0.f);
      a2s[r] = (_Float16)__builtin_amdgcn_exp2f(d2x * -0.72134752044448f);
      a2b[r] = (_Float16)__builtin_amdgcn_exp2f(d2b * -0.72134752044448f);
      float e2x = fmaxf(sxp + nx1[r] + gx1[r], 0.f);
      float e2b = fmaxf(e2x + (sfp + nf1[r] + gf1[r]), 0.f);
      a2s[4 + r] = (_Float16)__builtin_amdgcn_exp2f(e2x * -0.72134752044448f);
      a2b[4 + r] = (_Float16)__builtin_amdgcn_exp2f(e2b * -0.72134752044448f);
    }
    acc_s = __builtin_amdgcn_mfma_f32_16x16x32_f16(a2s, bq, acc_s, 0, 0, 0);
    acc_b = __builtin_amdgcn_mfma_f32_16x16x32_f16(a2b, bq, acc_b, 0, 0, 0);
  }

  // D layout: col = lane&15 (label slot), row = 4*(lane>>4) + r (p offset)
  int pout = ptile + g * 4;
  size_t base = ((size_t)seg * N + pout) * 16 + rm;
#pragma unroll
  for (int r = 0; r < 4; ++r) {
    ps[base + (size_t)r * 16] = acc_s[r];
    pb[base + (size_t)r * 16] = acc_b[r];
  }
}

__global__ __launch_bounds__(256) void reduce_kernel(const float* __restrict__ ps,
                                                     const float* __restrict__ pb,
                                                     float* __restrict__ S,
                                                     float* __restrict__ Bb,
                                                     int segs) {
  int p = blockIdx.x * 256 + threadIdx.x;
  f32x4 s0 = {0,0,0,0}, s1 = {0,0,0,0}, s2 = {0,0,0,0}, s3 = {0,0,0,0};
  f32x4 b0 = {0,0,0,0}, b1 = {0,0,0,0}, b2 = {0,0,0,0}, b3 = {0,0,0,0};
  for (int seg = 0; seg < segs; ++seg) {
    const f32x4* rs = (const f32x4*)(ps + ((size_t)seg * N + p) * 16);
    const f32x4* rb = (const f32x4*)(pb + ((size_t)seg * N + p) * 16);
    s0 += rs[0]; s1 += rs[1]; s2 += rs[2]; s3 += rs[3];
    b0 += rb[0]; b1 += rb[1]; b2 += rb[2]; b3 += rb[3];
  }
  float inv_s = 1.0f / s3[1];  // col 13 = norm
  float inv_b = 1.0f / b3[1];
  float sa[16], ba[16];
  *(f32x4*)(sa) = s0; *(f32x4*)(sa + 4) = s1; *(f32x4*)(sa + 8) = s2; *(f32x4*)(sa + 12) = s3;
  *(f32x4*)(ba) = b0; *(f32x4*)(ba + 4) = b1; *(f32x4*)(ba + 8) = b2; *(f32x4*)(ba + 12) = b3;
#pragma unroll
  for (int l = 0; l < L; ++l) {
    S[p * L + l] = sa[l] * inv_s;
    Bb[p * L + l] = ba[l] * inv_b;
  }
}

// faithful reshape-mixing
__global__ __launch_bounds__(256) void mix_kernel(const float* __restrict__ S,
                                                  const float* __restrict__ Bb,
                                                  const float* __restrict__ M1,
                                                  const float* __restrict__ M2,
                                                  const float* __restrict__ logits,
                                                  float* __restrict__ cur) {
  int i = blockIdx.x * 256 + threadIdx.x;
  if (i >= N * L) return;
  int r = i >> 13;
  int c = i & (N - 1);
  float v = 0.f;
#pragma unroll
  for (int j = 0; j < L; ++j) {
    v = fmaf(M1[r * L + j], S[j * N + c], v);
    v = fmaf(M2[r * L + j], Bb[j * N + c], v);
  }
  cur[i] = v + logits[i];
}

extern "C" void kernel_launch(void* const* d_in, const int* in_sizes, int n_in,
                              void* d_out, int out_size, void* d_ws, size_t ws_size,
                              hipStream_t stream) {
  const float* points = (const float*)d_in[0];
  const float* logits = (const float*)d_in[1];
  const float* Ws = (const float*)d_in[2];
  const float* Wb = (const float*)d_in[3];
  const float* C = (const float*)d_in[4];

  float* cur = (float*)d_out;

  // pick segs based on workspace budget
  size_t fixed_bytes = (size_t)(6 * N + 13 * N + 13 * N + 13 * N + 2 * N + 1024) * 4
                     + (size_t)512 * 64 * 8 * 2    // a1pack
                     + (size_t)256 * 64 * 8 * 2;   // qpack
  int segs = (ws_size >= fixed_bytes + (size_t)16 * N * 16 * 4 * 2) ? 16 : 8;

  float* w = (float*)d_ws;
  float* crd  = w;                        w += 6 * N;
  float* snx  = w;                        w += N;
  float* snf  = w;                        w += N;
  float* qtmp = w;                        w += (size_t)L * N;
  float* ps   = w;                        w += (size_t)segs * N * 16;
  float* pb   = w;                        w += (size_t)segs * N * 16;
  float* S    = w;                        w += (size_t)L * N;
  float* Bb   = w;                        w += (size_t)L * N;
  float* M1   = w;                        w += 256;
  float* M2   = w;                        w += 256;
  unsigned short* a1pack = (unsigned short*)w;           // 512*64*8 u16 = 512 KB
  unsigned short* qpack  = a1pack + (size_t)512 * 64 * 8; // 256*64*8 u16 = 256 KB

  prep_kernel<<<N / 256, 256, 0, stream>>>(points, logits, crd, cur, snx, snf, a1pack, qpack);
  mprep_kernel<<<1, 256, 0, stream>>>(Ws, Wb, C, M1, M2);

  for (int it = 0; it < 5; ++it) {
    softmax_kernel<<<L, 1024, 0, stream>>>(cur, qtmp, qpack);
    filter_kernel<<<dim3(N / 64, segs), 256, 0, stream>>>(crd, snx, snf, a1pack, qpack, ps, pb, segs);
    reduce_kernel<<<N / 256, 256, 0, stream>>>(ps, pb, S, Bb, segs);
    mix_kernel<<<(N * L + 255) / 256, 256, 0, stream>>>(S, Bb, M1, M2, logits, cur);
  }
}

// Round 4
// 241.911 us; speedup vs baseline: 2.6352x; 1.4359x over previous
//
#include <hip/hip_runtime.h>

#define N 8192
#define L 13

typedef _Float16 f16x8 __attribute__((ext_vector_type(8)));
typedef _Float16 f16x2 __attribute__((ext_vector_type(2)));
typedef float f32x4 __attribute__((ext_vector_type(4)));

union F16x8U { f16x8 v; f16x2 h[4]; };

#define C1 (-0.72134752044448f)   // -0.5/ln2 : exp(-0.5 d2) = exp2(C1*d2)
#define C2 (1.44269504088896f)    // -2*C1 (also log2(e) for softmax exp)

// a1pack [spair(256)][lane(64)][j(8)] f16 — A-frags for arg-MFMAs, k-point K:
//   lane  0..15 (g0): K=spair*32+rm    : {x,y,z, |xyz|^2, 1, 0,0,0}      (spatial, subtile 0)
//   lane 16..31 (g1): K=spair*32+rm    : {x,y,z,u,v,w, |all|^2, 1}       (bilateral, subtile 0)
//   lane 32..47 (g2): K=spair*32+16+rm : spatial quintuple                (subtile 1)
//   lane 48..63 (g3): K=spair*32+16+rm : bilateral octuple                (subtile 1)
// qpack [kc(256)][lane=g*16+col][j(8)] f16 = q[kc*32 + phys(g,j)][col],
//   phys(g,j) = j<4 ? 4g+j : 16+4g+(j-4); col13 = 1.0 (norm), col14/15 = 0

__global__ __launch_bounds__(256) void prep_kernel(const float* __restrict__ points,
                                                   const float* __restrict__ logits,
                                                   float* __restrict__ crd,
                                                   float* __restrict__ cur,
                                                   float* __restrict__ snx,
                                                   float* __restrict__ snf,
                                                   float* __restrict__ et,
                                                   unsigned short* __restrict__ a1pack,
                                                   unsigned short* __restrict__ qpack) {
  int p = blockIdx.x * 256 + threadIdx.x;
  float c6[6];
#pragma unroll
  for (int d = 0; d < 6; ++d) { c6[d] = points[p * 6 + d]; crd[d * N + p] = c6[d]; }
  float sx = c6[0] * c6[0] + c6[1] * c6[1] + c6[2] * c6[2];
  float sf = c6[3] * c6[3] + c6[4] * c6[4] + c6[5] * c6[5];
  snx[p] = sx; snf[p] = sf;
#pragma unroll
  for (int l = 0; l < L; ++l) {
    float lg = logits[p * L + l];
    cur[p * L + l] = lg;
    et[(size_t)l * N + p] = __builtin_amdgcn_exp2f(lg * C2);
  }
  int spair = p >> 5, w = p & 31, rm = w & 15;
  int laneS = (w < 16 ? 0 : 32) + rm;
  int laneB = (w < 16 ? 16 : 48) + rm;
  f16x8 vs = { (_Float16)c6[0], (_Float16)c6[1], (_Float16)c6[2],
               (_Float16)sx, (_Float16)1.0f, (_Float16)0.0f, (_Float16)0.0f, (_Float16)0.0f };
  f16x8 vb = { (_Float16)c6[0], (_Float16)c6[1], (_Float16)c6[2],
               (_Float16)c6[3], (_Float16)c6[4], (_Float16)c6[5],
               (_Float16)(sx + sf), (_Float16)1.0f };
  ((f16x8*)a1pack)[(size_t)spair * 64 + laneS] = vs;
  ((f16x8*)a1pack)[(size_t)spair * 64 + laneB] = vb;

  int kc = p >> 5, kk = p & 31;
  int g = (kk < 16) ? (kk >> 2) : ((kk - 16) >> 2);
  int j = (kk < 16) ? (kk & 3) : (4 + (kk & 3));
  qpack[((size_t)kc * 64 + g * 16 + 13) * 8 + j] = 0x3C00;  // f16 1.0
  qpack[((size_t)kc * 64 + g * 16 + 14) * 8 + j] = 0;
  qpack[((size_t)kc * 64 + g * 16 + 15) * 8 + j] = 0;
}

__global__ void mprep_kernel(const float* __restrict__ Ws, const float* __restrict__ Wb,
                             const float* __restrict__ C, float* __restrict__ M1,
                             float* __restrict__ M2) {
  int i = threadIdx.x;
  if (i < L * L) {
    int r = i / L, c = i % L;
    float a = 0.f, b = 0.f;
    for (int j = 0; j < L; ++j) {
      a += C[r * L + j] * Ws[j * L + c];
      b += C[r * L + j] * Wb[j * L + c];
    }
    M1[i] = a; M2[i] = b;
  }
}

// per-label-column partial sums of et (softmax denominator, no max-subtraction needed)
__global__ __launch_bounds__(256) void colsum_kernel(const float* __restrict__ et,
                                                     float* __restrict__ part) {
  int l = blockIdx.x, s = blockIdx.y, t = threadIdx.x;
  const float4 v = *(const float4*)(et + (size_t)l * N + s * 1024 + t * 4);
  __shared__ float red[256];
  red[t] = v.x + v.y + v.z + v.w;
  __syncthreads();
  for (int d = 128; d > 0; d >>= 1) {
    if (t < d) red[t] += red[t + d];
    __syncthreads();
  }
  if (t == 0) part[l * 8 + s] = red[0];
}

// normalize q = et/colsum, convert to f16, scatter into qpack fragment order
__global__ __launch_bounds__(256) void pack_kernel(const float* __restrict__ et,
                                                   const float* __restrict__ part,
                                                   unsigned short* __restrict__ qpack) {
  int p = blockIdx.x * 256 + threadIdx.x;
  int kc = p >> 5, kk = p & 31;
  int g = (kk < 16) ? (kk >> 2) : ((kk - 16) >> 2);
  int j = (kk < 16) ? (kk & 3) : (4 + (kk & 3));
  size_t base = ((size_t)kc * 64 + g * 16) * 8 + j;
#pragma unroll
  for (int l = 0; l < L; ++l) {
    float s = 0.f;
#pragma unroll
    for (int k = 0; k < 8; ++k) s += part[l * 8 + k];
    _Float16 q = (_Float16)(et[(size_t)l * N + p] / s);
    qpack[base + (size_t)l * 8] = *(unsigned short*)&q;
  }
}

// hot kernel: 4 independent waves/block, 16 p-rows each.
// Dot-MFMAs emit the complete exp2 arguments; VALU does only exp + pack.
__global__ __launch_bounds__(256) void filter_kernel(const float* __restrict__ crd,
                                                     const float* __restrict__ snx,
                                                     const float* __restrict__ snf,
                                                     const unsigned short* __restrict__ a1pack,
                                                     const unsigned short* __restrict__ qpack,
                                                     float* __restrict__ ps,
                                                     float* __restrict__ pb,
                                                     int segs) {
  int tid = threadIdx.x;
  int lane = tid & 63, wave = tid >> 6;
  int g = lane >> 4, rm = lane & 15;
  int ptile = blockIdx.x * 64 + wave * 16;
  int p = ptile + rm;
  int seg = blockIdx.y;
  int nsp = (N / segs) >> 5;

  float x0 = crd[p], x1 = crd[N + p], x2 = crd[2 * N + p];
  float f0 = crd[3 * N + p], f1 = crd[4 * N + p], f2 = crd[5 * N + p];
  float sx = snx[p], sf = snf[p];

  f16x8 spat = { (_Float16)(C2 * x0), (_Float16)(C2 * x1), (_Float16)(C2 * x2),
                 (_Float16)C1, (_Float16)(C1 * sx),
                 (_Float16)0.0f, (_Float16)0.0f, (_Float16)0.0f };
  f16x8 bil  = { (_Float16)(C2 * x0), (_Float16)(C2 * x1), (_Float16)(C2 * x2),
                 (_Float16)(C2 * f0), (_Float16)(C2 * f1), (_Float16)(C2 * f2),
                 (_Float16)C1, (_Float16)(C1 * (sx + sf)) };
  f16x8 z8 = {0, 0, 0, 0, 0, 0, 0, 0};
  f16x8 Bs0 = (g == 0) ? spat : z8;
  f16x8 Bb0 = (g == 1) ? bil : z8;
  f16x8 Bs1 = (g == 2) ? spat : z8;
  f16x8 Bb1 = (g == 3) ? bil : z8;

  f32x4 acc_s = {0.f, 0.f, 0.f, 0.f};
  f32x4 acc_b = {0.f, 0.f, 0.f, 0.f};
  const f32x4 zero = {0.f, 0.f, 0.f, 0.f};
  const f16x8* a1 = (const f16x8*)a1pack;
  const f16x8* qp = (const f16x8*)qpack;

#define PK(dst, va, vb_) { auto _r = __builtin_amdgcn_cvt_pkrtz(va, vb_); dst = *(f16x2*)&_r; }

  int sp0 = seg * nsp;
  for (int sp = sp0; sp < sp0 + nsp; ++sp) {
    f16x8 A  = a1[(size_t)sp * 64 + lane];
    f16x8 bq = qp[(size_t)sp * 64 + lane];
    f32x4 ax0 = __builtin_amdgcn_mfma_f32_16x16x32_f16(A, Bs0, zero, 0, 0, 0);
    f32x4 ab0 = __builtin_amdgcn_mfma_f32_16x16x32_f16(A, Bb0, zero, 0, 0, 0);
    f32x4 ax1 = __builtin_amdgcn_mfma_f32_16x16x32_f16(A, Bs1, zero, 0, 0, 0);
    f32x4 ab1 = __builtin_amdgcn_mfma_f32_16x16x32_f16(A, Bb1, zero, 0, 0, 0);
    F16x8U us, ub;
    PK(us.h[0], __builtin_amdgcn_exp2f(ax0[0]), __builtin_amdgcn_exp2f(ax0[1]));
    PK(us.h[1], __builtin_amdgcn_exp2f(ax0[2]), __builtin_amdgcn_exp2f(ax0[3]));
    PK(us.h[2], __builtin_amdgcn_exp2f(ax1[0]), __builtin_amdgcn_exp2f(ax1[1]));
    PK(us.h[3], __builtin_amdgcn_exp2f(ax1[2]), __builtin_amdgcn_exp2f(ax1[3]));
    PK(ub.h[0], __builtin_amdgcn_exp2f(ab0[0]), __builtin_amdgcn_exp2f(ab0[1]));
    PK(ub.h[1], __builtin_amdgcn_exp2f(ab0[2]), __builtin_amdgcn_exp2f(ab0[3]));
    PK(ub.h[2], __builtin_amdgcn_exp2f(ab1[0]), __builtin_amdgcn_exp2f(ab1[1]));
    PK(ub.h[3], __builtin_amdgcn_exp2f(ab1[2]), __builtin_amdgcn_exp2f(ab1[3]));
    acc_s = __builtin_amdgcn_mfma_f32_16x16x32_f16(us.v, bq, acc_s, 0, 0, 0);
    acc_b = __builtin_amdgcn_mfma_f32_16x16x32_f16(ub.v, bq, acc_b, 0, 0, 0);
  }

  // D layout: col(lane&15) = label slot, row = 4*(lane>>4)+r = p offset
  int pout = ptile + g * 4;
  size_t base = ((size_t)seg * N + pout) * 16 + rm;
#pragma unroll
  for (int r = 0; r < 4; ++r) {
    ps[base + (size_t)r * 16] = acc_s[r];
    pb[base + (size_t)r * 16] = acc_b[r];
  }
}

__global__ __launch_bounds__(256) void reduce_kernel(const float* __restrict__ ps,
                                                     const float* __restrict__ pb,
                                                     float* __restrict__ S,
                                                     float* __restrict__ Bb,
                                                     int segs) {
  int gid = blockIdx.x * 256 + threadIdx.x;
  int p = gid & (N - 1);
  const float* src = (gid < N) ? ps : pb;
  float* dst = (gid < N) ? S : Bb;
  f32x4 a0 = {0,0,0,0}, a1_ = {0,0,0,0}, a2 = {0,0,0,0}, a3 = {0,0,0,0};
  for (int seg = 0; seg < segs; ++seg) {
    const f32x4* r4 = (const f32x4*)(src + ((size_t)seg * N + p) * 16);
    a0 += r4[0]; a1_ += r4[1]; a2 += r4[2]; a3 += r4[3];
  }
  float inv = 1.0f / a3[1];  // col 13 = norm
  float arr[16];
  *(f32x4*)(arr) = a0; *(f32x4*)(arr + 4) = a1_;
  *(f32x4*)(arr + 8) = a2; *(f32x4*)(arr + 12) = a3;
#pragma unroll
  for (int l = 0; l < L; ++l) dst[p * L + l] = arr[l] * inv;
}

// faithful reshape-mixing + emit transposed exp for next iteration's softmax
__global__ __launch_bounds__(256) void mix_kernel(const float* __restrict__ S,
                                                  const float* __restrict__ Bb,
                                                  const float* __restrict__ M1,
                                                  const float* __restrict__ M2,
                                                  const float* __restrict__ logits,
                                                  float* __restrict__ cur,
                                                  float* __restrict__ et) {
  int i = blockIdx.x * 256 + threadIdx.x;
  if (i >= N * L) return;
  int r = i >> 13;
  int c = i & (N - 1);
  float v = 0.f;
#pragma unroll
  for (int j = 0; j < L; ++j) {
    v = fmaf(M1[r * L + j], S[j * N + c], v);
    v = fmaf(M2[r * L + j], Bb[j * N + c], v);
  }
  float o = v + logits[i];
  cur[i] = o;
  int p = i / 13, l = i - p * 13;
  et[(size_t)l * N + p] = __builtin_amdgcn_exp2f(o * C2);
}

extern "C" void kernel_launch(void* const* d_in, const int* in_sizes, int n_in,
                              void* d_out, int out_size, void* d_ws, size_t ws_size,
                              hipStream_t stream) {
  const float* points = (const float*)d_in[0];
  const float* logits = (const float*)d_in[1];
  const float* Ws = (const float*)d_in[2];
  const float* Wb = (const float*)d_in[3];
  const float* C = (const float*)d_in[4];

  float* cur = (float*)d_out;

  size_t fixed_words = (size_t)6 * N + 2 * N + (size_t)L * N          // crd,snx,snf,et
                     + (size_t)L * N * 2 + 512 + 128                  // S,Bb,M1,M2,part
                     + (size_t)256 * 64 * 8 / 2 * 2;                  // a1pack+qpack (u16)
  int segs = (ws_size >= (fixed_words + (size_t)16 * N * 16 * 2) * 4) ? 16 : 8;

  float* w = (float*)d_ws;
  float* crd  = w;                        w += 6 * N;
  float* snx  = w;                        w += N;
  float* snf  = w;                        w += N;
  float* et   = w;                        w += (size_t)L * N;
  float* ps   = w;                        w += (size_t)segs * N * 16;
  float* pb   = w;                        w += (size_t)segs * N * 16;
  float* S    = w;                        w += (size_t)L * N;
  float* Bb   = w;                        w += (size_t)L * N;
  float* M1   = w;                        w += 256;
  float* M2   = w;                        w += 256;
  float* part = w;                        w += 128;
  unsigned short* a1pack = (unsigned short*)w;              // 256*64*8 u16 = 256 KB
  unsigned short* qpack  = a1pack + (size_t)256 * 64 * 8;   // 256 KB

  prep_kernel<<<N / 256, 256, 0, stream>>>(points, logits, crd, cur, snx, snf, et, a1pack, qpack);
  mprep_kernel<<<1, 256, 0, stream>>>(Ws, Wb, C, M1, M2);

  for (int it = 0; it < 5; ++it) {
    colsum_kernel<<<dim3(L, 8), 256, 0, stream>>>(et, part);
    pack_kernel<<<N / 256, 256, 0, stream>>>(et, part, qpack);
    filter_kernel<<<dim3(N / 64, segs), 256, 0, stream>>>(crd, snx, snf, a1pack, qpack, ps, pb, segs);
    reduce_kernel<<<2 * N / 256, 256, 0, stream>>>(ps, pb, S, Bb, segs);
    mix_kernel<<<(N * L + 255) / 256, 256, 0, stream>>>(S, Bb, M1, M2, logits, cur, et);
  }
}

// Round 5
// 178.513 us; speedup vs baseline: 3.5710x; 1.3551x over previous
//
#include <hip/hip_runtime.h>

#define N 8192
#define L 13
#define SEGS 8
#define NSP (N / SEGS / 32)   // 32 MFMA-pair iterations per filter block
#define PARTROWS 416          // = N*L/256 (mix grid); prep fills rows 0..31, zeros rest

typedef _Float16 f16x8 __attribute__((ext_vector_type(8)));
typedef _Float16 f16x2 __attribute__((ext_vector_type(2)));
typedef float f32x4 __attribute__((ext_vector_type(4)));
union F16x8U { f16x8 v; f16x2 h[4]; };

#define C1 (-0.72134752044448f)   // -0.5/ln2
#define C2 (1.44269504088896f)    // log2(e)
#define EBIAS 6.0f                // e' = exp2(C2*x - EBIAS): keeps f16 in range; cancels in e'/D'

// a1pack [spair(256)][lane(64)][j(8)] f16 — A-frags (k-side quintuple/octuple), as round 4.
// qpack  [kc(256)][lane=g*16+col][j(8)] f16 = e'[kc*32+phys(g,j)][col]; col13=1.0, col14/15=0.
//   phys(g,j) = j<4 ? 4g+j : 16+4g+(j-4)

__global__ __launch_bounds__(256) void prep_kernel(const float* __restrict__ points,
                                                   const float* __restrict__ logits,
                                                   float* __restrict__ crd,
                                                   float* __restrict__ snx,
                                                   float* __restrict__ snf,
                                                   float* __restrict__ part,
                                                   unsigned short* __restrict__ a1pack,
                                                   unsigned short* __restrict__ qpack) {
  int t = threadIdx.x;
  int p = blockIdx.x * 256 + t;
  float c6[6];
#pragma unroll
  for (int d = 0; d < 6; ++d) { c6[d] = points[p * 6 + d]; crd[d * N + p] = c6[d]; }
  float sx = c6[0] * c6[0] + c6[1] * c6[1] + c6[2] * c6[2];
  float sf = c6[3] * c6[3] + c6[4] * c6[4] + c6[5] * c6[5];
  snx[p] = sx; snf[p] = sf;

  int spair = p >> 5, w = p & 31, rm = w & 15;
  int laneS = (w < 16 ? 0 : 32) + rm;
  int laneB = (w < 16 ? 16 : 48) + rm;
  f16x8 vs = { (_Float16)c6[0], (_Float16)c6[1], (_Float16)c6[2],
               (_Float16)sx, (_Float16)1.0f, (_Float16)0.0f, (_Float16)0.0f, (_Float16)0.0f };
  f16x8 vb = { (_Float16)c6[0], (_Float16)c6[1], (_Float16)c6[2],
               (_Float16)c6[3], (_Float16)c6[4], (_Float16)c6[5],
               (_Float16)(sx + sf), (_Float16)1.0f };
  ((f16x8*)a1pack)[(size_t)spair * 64 + laneS] = vs;
  ((f16x8*)a1pack)[(size_t)spair * 64 + laneB] = vb;

  int kc = p >> 5, kk = p & 31;
  int g = (kk < 16) ? (kk >> 2) : ((kk - 16) >> 2);
  int j2 = (kk < 16) ? (kk & 3) : (4 + (kk & 3));
  size_t qb = ((size_t)kc * 64 + g * 16) * 8 + j2;
  qpack[qb + 13 * 8] = 0x3C00;  // f16 1.0 (norm column)
  qpack[qb + 14 * 8] = 0;
  qpack[qb + 15 * 8] = 0;

  // initial unnormalized-softmax pack + per-block label sums
  __shared__ float buf[13][256];
#pragma unroll
  for (int l = 0; l < L; ++l) {
    float e = __builtin_amdgcn_exp2f(logits[p * L + l] * C2 - EBIAS);
    _Float16 h = (_Float16)e;
    qpack[qb + (size_t)l * 8] = *(unsigned short*)&h;
    buf[l][t] = e;
  }
  __syncthreads();
  for (int s = 128; s >= 1; s >>= 1) {
    if (t < s) {
#pragma unroll
      for (int l = 0; l < L; ++l) buf[l][t] += buf[l][t + s];
    }
    __syncthreads();
  }
  if (t < L) part[blockIdx.x * 16 + t] = buf[t][0];
  // zero part rows 32..415 (this call's mix will overwrite them each iteration)
  if (t < 192) part[(32 + blockIdx.x * 12 + (t >> 4)) * 16 + (t & 15)] = 0.f;
}

__global__ void mprep_kernel(const float* __restrict__ Ws, const float* __restrict__ Wb,
                             const float* __restrict__ C, float* __restrict__ M1,
                             float* __restrict__ M2) {
  int i = threadIdx.x;
  if (i < L * L) {
    int r = i / L, c = i % L;
    float a = 0.f, b = 0.f;
    for (int j = 0; j < L; ++j) {
      a += C[r * L + j] * Ws[j * L + c];
      b += C[r * L + j] * Wb[j * L + c];
    }
    M1[i] = a; M2[i] = b;
  }
}

// hot kernel: 4 independent waves/block, 16 p-rows each.
// Dot-MFMAs emit the complete exp2 arguments; VALU does only exp + pack.
__global__ __launch_bounds__(256) void filter_kernel(const float* __restrict__ crd,
                                                     const float* __restrict__ snx,
                                                     const float* __restrict__ snf,
                                                     const unsigned short* __restrict__ a1pack,
                                                     const unsigned short* __restrict__ qpack,
                                                     float* __restrict__ ps,
                                                     float* __restrict__ pb) {
  int tid = threadIdx.x;
  int lane = tid & 63, wave = tid >> 6;
  int g = lane >> 4, rm = lane & 15;
  int ptile = blockIdx.x * 64 + wave * 16;
  int p = ptile + rm;
  int seg = blockIdx.y;

  float x0 = crd[p], x1 = crd[N + p], x2 = crd[2 * N + p];
  float f0 = crd[3 * N + p], f1 = crd[4 * N + p], f2 = crd[5 * N + p];
  float sx = snx[p], sf = snf[p];

  f16x8 spat = { (_Float16)(C2 * x0), (_Float16)(C2 * x1), (_Float16)(C2 * x2),
                 (_Float16)C1, (_Float16)(C1 * sx),
                 (_Float16)0.0f, (_Float16)0.0f, (_Float16)0.0f };
  f16x8 bil  = { (_Float16)(C2 * x0), (_Float16)(C2 * x1), (_Float16)(C2 * x2),
                 (_Float16)(C2 * f0), (_Float16)(C2 * f1), (_Float16)(C2 * f2),
                 (_Float16)C1, (_Float16)(C1 * (sx + sf)) };
  f16x8 z8 = {0, 0, 0, 0, 0, 0, 0, 0};
  f16x8 Bs0 = (g == 0) ? spat : z8;
  f16x8 Bb0 = (g == 1) ? bil : z8;
  f16x8 Bs1 = (g == 2) ? spat : z8;
  f16x8 Bb1 = (g == 3) ? bil : z8;

  f32x4 acc_s = {0.f, 0.f, 0.f, 0.f};
  f32x4 acc_b = {0.f, 0.f, 0.f, 0.f};
  const f32x4 zero = {0.f, 0.f, 0.f, 0.f};
  const f16x8* a1 = (const f16x8*)a1pack;
  const f16x8* qp = (const f16x8*)qpack;

#define PK(dst, va, vb_) { auto _r = __builtin_amdgcn_cvt_pkrtz(va, vb_); dst = *(f16x2*)&_r; }

  int sp0 = seg * NSP;
#pragma unroll 2
  for (int sp = sp0; sp < sp0 + NSP; ++sp) {
    f16x8 A  = a1[(size_t)sp * 64 + lane];
    f16x8 bq = qp[(size_t)sp * 64 + lane];
    f32x4 ax0 = __builtin_amdgcn_mfma_f32_16x16x32_f16(A, Bs0, zero, 0, 0, 0);
    f32x4 ab0 = __builtin_amdgcn_mfma_f32_16x16x32_f16(A, Bb0, zero, 0, 0, 0);
    f32x4 ax1 = __builtin_amdgcn_mfma_f32_16x16x32_f16(A, Bs1, zero, 0, 0, 0);
    f32x4 ab1 = __builtin_amdgcn_mfma_f32_16x16x32_f16(A, Bb1, zero, 0, 0, 0);
    F16x8U us, ub;
    PK(us.h[0], __builtin_amdgcn_exp2f(ax0[0]), __builtin_amdgcn_exp2f(ax0[1]));
    PK(us.h[1], __builtin_amdgcn_exp2f(ax0[2]), __builtin_amdgcn_exp2f(ax0[3]));
    PK(us.h[2], __builtin_amdgcn_exp2f(ax1[0]), __builtin_amdgcn_exp2f(ax1[1]));
    PK(us.h[3], __builtin_amdgcn_exp2f(ax1[2]), __builtin_amdgcn_exp2f(ax1[3]));
    PK(ub.h[0], __builtin_amdgcn_exp2f(ab0[0]), __builtin_amdgcn_exp2f(ab0[1]));
    PK(ub.h[1], __builtin_amdgcn_exp2f(ab0[2]), __builtin_amdgcn_exp2f(ab0[3]));
    PK(ub.h[2], __builtin_amdgcn_exp2f(ab1[0]), __builtin_amdgcn_exp2f(ab1[1]));
    PK(ub.h[3], __builtin_amdgcn_exp2f(ab1[2]), __builtin_amdgcn_exp2f(ab1[3]));
    acc_s = __builtin_amdgcn_mfma_f32_16x16x32_f16(us.v, bq, acc_s, 0, 0, 0);
    acc_b = __builtin_amdgcn_mfma_f32_16x16x32_f16(ub.v, bq, acc_b, 0, 0, 0);
  }

  int pout = ptile + g * 4;
  size_t base = ((size_t)seg * N + pout) * 16 + rm;
#pragma unroll
  for (int r = 0; r < 4; ++r) {
    ps[base + (size_t)r * 16] = acc_s[r];
    pb[base + (size_t)r * 16] = acc_b[r];
  }
}

// 256 blocks; tasks = (point within 32) x (src: S/B) x (col-quad).
// Folds BOTH 1/norm (col 13) and 1/D_l (softmax denominator, from part) into S/Bb.
__global__ __launch_bounds__(256) void reduce_kernel(const float* __restrict__ ps,
                                                     const float* __restrict__ pb,
                                                     const float* __restrict__ part,
                                                     float* __restrict__ S,
                                                     float* __restrict__ Bb) {
  int t = threadIdx.x;
  __shared__ float buf[13][256];
#pragma unroll
  for (int l = 0; l < L; ++l) {
    float v = part[t * 16 + l];
    if (t < PARTROWS - 256) v += part[(t + 256) * 16 + l];
    buf[l][t] = v;
  }
  __syncthreads();
  for (int s = 128; s >= 1; s >>= 1) {
    if (t < s) {
#pragma unroll
      for (int l = 0; l < L; ++l) buf[l][t] += buf[l][t + s];
    }
    __syncthreads();
  }

  int q = t & 3, src = (t >> 2) & 1, pi = t >> 3;
  int p = blockIdx.x * 32 + pi;
  const float* basep = src ? pb : ps;
  f32x4 acc = {0.f, 0.f, 0.f, 0.f};
#pragma unroll
  for (int seg = 0; seg < SEGS; ++seg)
    acc += *(const f32x4*)(basep + ((size_t)seg * N + p) * 16 + q * 4);

  __shared__ float nrm[64];
  if (q == 3) nrm[pi * 2 + src] = acc[1];  // col 13 = norm
  __syncthreads();
  float inv_norm = 1.0f / nrm[pi * 2 + src];
  float* dst = src ? Bb : S;
#pragma unroll
  for (int e = 0; e < 4; ++e) {
    int col = q * 4 + e;
    if (col < L) {
      float invD = 1.0f / ((float*)buf)[col * 256];  // buf[col][0]
      dst[(size_t)p * L + col] = acc[e] * invD * inv_norm;
    }
  }
}

// faithful reshape-mixing + next iteration's unnormalized softmax pack + label partial sums
__global__ __launch_bounds__(256) void mix_kernel(const float* __restrict__ S,
                                                  const float* __restrict__ Bb,
                                                  const float* __restrict__ M1,
                                                  const float* __restrict__ M2,
                                                  const float* __restrict__ logits,
                                                  float* __restrict__ cur,
                                                  unsigned short* __restrict__ qpack,
                                                  float* __restrict__ part) {
  int t = threadIdx.x;
  int i = blockIdx.x * 256 + t;           // grid is exactly N*L/256 = 416
  int c = i & (N - 1);
  int r = i >> 13;
  float v = 0.f;
#pragma unroll
  for (int j = 0; j < L; ++j) {
    v = fmaf(M1[r * L + j], S[(size_t)j * N + c], v);
    v = fmaf(M2[r * L + j], Bb[(size_t)j * N + c], v);
  }
  float o = v + logits[i];
  cur[i] = o;

  float e = __builtin_amdgcn_exp2f(o * C2 - EBIAS);
  unsigned int pr = (unsigned int)i / 13u;
  int l = i - pr * 13;
  int kc = pr >> 5, kk = pr & 31;
  int g = (kk < 16) ? (kk >> 2) : ((kk - 16) >> 2);
  int j2 = (kk < 16) ? (kk & 3) : (4 + (kk & 3));
  _Float16 h = (_Float16)e;
  qpack[((size_t)kc * 64 + g * 16 + l) * 8 + j2] = *(unsigned short*)&h;

  // deterministic per-block label sums: slot (l, t/13) is bijective in t
  __shared__ float buf[260];
  if (t < 260) buf[t] = 0.f;
  __syncthreads();
  buf[l * 20 + t / 13u] = e;
  __syncthreads();
  if (t < L) {
    float s_ = 0.f;
#pragma unroll
    for (int k = 0; k < 20; ++k) s_ += buf[t * 20 + k];
    part[blockIdx.x * 16 + t] = s_;
  }
}

extern "C" void kernel_launch(void* const* d_in, const int* in_sizes, int n_in,
                              void* d_out, int out_size, void* d_ws, size_t ws_size,
                              hipStream_t stream) {
  const float* points = (const float*)d_in[0];
  const float* logits = (const float*)d_in[1];
  const float* Ws = (const float*)d_in[2];
  const float* Wb = (const float*)d_in[3];
  const float* C = (const float*)d_in[4];

  float* cur = (float*)d_out;

  float* w = (float*)d_ws;
  float* crd  = w;                        w += 6 * N;
  float* snx  = w;                        w += N;
  float* snf  = w;                        w += N;
  float* ps   = w;                        w += (size_t)SEGS * N * 16;
  float* pb   = w;                        w += (size_t)SEGS * N * 16;
  float* S    = w;                        w += (size_t)L * N + 64;
  float* Bb   = w;                        w += (size_t)L * N + 64;
  float* M1   = w;                        w += 256;
  float* M2   = w;                        w += 256;
  float* part = w;                        w += PARTROWS * 16;
  unsigned short* a1pack = (unsigned short*)w;              // 256*64*8 u16 = 256 KB
  unsigned short* qpack  = a1pack + (size_t)256 * 64 * 8;   // 256 KB

  prep_kernel<<<N / 256, 256, 0, stream>>>(points, logits, crd, snx, snf, part, a1pack, qpack);
  mprep_kernel<<<1, 256, 0, stream>>>(Ws, Wb, C, M1, M2);

  for (int it = 0; it < 5; ++it) {
    filter_kernel<<<dim3(N / 64, SEGS), 256, 0, stream>>>(crd, snx, snf, a1pack, qpack, ps, pb);
    reduce_kernel<<<N / 32, 256, 0, stream>>>(ps, pb, part, S, Bb);
    mix_kernel<<<(N * L) / 256, 256, 0, stream>>>(S, Bb, M1, M2, logits, cur, qpack, part);
  }
}